// Round 7
// baseline (31.100 us; speedup 1.0000x reference)
//
#include <hip/hip_runtime.h>

// SuperResolve: A=4 frames, n=4, c=3, h=w=256, S=2 -> out (4,3,512,512) fp32
// R7: LDS-staged. Block = 256 thr = 4 waves over 128-px half-row (y0 uniform);
// waves 0,1 frames {0,1}; waves 2,3 frames {2,3}. Staging: 72 segments
// (4 frames x 6 planes x 3 rows) x 133 cols in LDS (stride 136, 39.2KB),
// loaded with coalesced float4 (center) + 144 halo dwords. Compute reads LDS
// (stride-1, conflict-free); arithmetic identical to R6 (bit-exact copy).
// Reduction buffer aliases staging LDS after a barrier.
// R3 lesson: no waves/EU cap (spills). R4: >=2048 blocks. R6: SGPR bases.

#define AF      4
#define NB      4
#define CH      3
#define H       256
#define W       256
#define SH      512
#define SW      512
#define HW      (H*W)
#define SHW     (SH*SW)
#define RADIUS  4.0f
// 0.25 (LR displacement scaling) * 0.5*log2(e): weight = exp2(-dist')
#define MSCALE  0.18033688011112042f
// clamp-hi: 20 * 0.5*log2(e)
#define CLHI    14.426950408889634f
#define SEGW    136   // floats per staged segment; col 3 = x(base-1), 4..131 = center, 132 = xbase+128

typedef float v2f __attribute__((ext_vector_type(2)));

__global__ __launch_bounds__(256) void superresolve_kernel(
    const float* __restrict__ alts,     // [AF][NB][CH][H][W]
    const float* __restrict__ offsets,  // [AF][NB][2][H][W]
    const float* __restrict__ qs,       // [AF][NB][H][W]
    const float* __restrict__ o11,      // [NB][SH][SW]
    const float* __restrict__ o12,
    const float* __restrict__ o21,
    const float* __restrict__ o22,
    float* __restrict__ out)            // [NB][CH][SH][SW]
{
    __shared__ float lds[72 * SEGW];    // 39168 B -> 4 blocks/CU

    const int tid   = threadIdx.x;
    const int wv    = tid >> 6;
    const int lane  = tid & 63;
    const int fpair = wv >> 1;                  // 0: frames {0,1}; 1: {2,3}
    const int pix   = ((wv & 1) << 6) + lane;   // 0..127

    // bijective XCD swizzle over 2048 blocks
    const int bid = blockIdx.x;
    const int swz = (bid & 7) * 256 + (bid >> 3);

    const int xbase = (swz & 1) << 7;           // 0 or 128
    const int y0  = __builtin_amdgcn_readfirstlane((swz >> 1) & (H - 1));
    const int nn  = __builtin_amdgcn_readfirstlane(swz >> 9);
    const int af0 = __builtin_amdgcn_readfirstlane(fpair << 1);
    const int x0  = xbase + pix;

    auto plane_ptr = [&](int a, int p) -> const float* {
        const size_t fb = (size_t)(a * NB + nn);
        if (p < 2)  return offsets + fb * 2 * HW + (size_t)p * HW;
        if (p == 2) return qs + fb * HW;
        return alts + (fb * CH + (size_t)(p - 3)) * HW;
    };

    // ---- o-matrix loads (independent of staging; issue early) ----
    const int obase = (nn * SH + 2 * y0) * SW + 2 * x0;
    const float2 v11a = *(const float2*)(o11 + obase);
    const float2 v11b = *(const float2*)(o11 + obase + SW);
    const float2 v12a = *(const float2*)(o12 + obase);
    const float2 v12b = *(const float2*)(o12 + obase + SW);
    const float2 v21a = *(const float2*)(o21 + obase);
    const float2 v21b = *(const float2*)(o21 + obase + SW);
    const float2 v22a = *(const float2*)(o22 + obase);
    const float2 v22b = *(const float2*)(o22 + obase + SW);

    // ---- cooperative staging: 72 segs x (128 center + 2 halo) ----
    {
        const int s0 = tid >> 5;                // 0..7
        const int j  = tid & 31;
        #pragma unroll
        for (int it = 0; it < 9; ++it) {
            const int s  = it * 8 + s0;         // 0..71
            const int a  = s / 18;
            const int pr = s - a * 18;
            const int p  = pr / 3;
            const int r  = pr - p * 3;
            const int row = min(max(y0 + r - 1, 0), H - 1);
            const float* gp = plane_ptr(a, p) + row * W + xbase + j * 4;
            const float4 v = *(const float4*)gp;
            *(float4*)&lds[s * SEGW + 4 + j * 4] = v;   // 16B-aligned
        }
        if (tid < 144) {
            const int s    = tid >> 1;
            const int side = tid & 1;
            const int a  = s / 18;
            const int pr = s - a * 18;
            const int p  = pr / 3;
            const int r  = pr - p * 3;
            const int row = min(max(y0 + r - 1, 0), H - 1);
            const int gx  = side ? min(xbase + 128, W - 1) : max(xbase - 1, 0);
            lds[s * SEGW + (side ? 132 : 3)] = plane_ptr(a, p)[row * W + gx];
        }
    }

    // ---- per-subpixel o-matrices as sx-pairs (indexed by sy) ----
    v2f m11v[2], m12v[2], m22v[2];
    m11v[0] = (v2f){MSCALE * v11a.x, MSCALE * v11a.y};
    m11v[1] = (v2f){MSCALE * v11b.x, MSCALE * v11b.y};
    m12v[0] = (v2f){MSCALE * (v12a.x + v21a.x), MSCALE * (v12a.y + v21a.y)};
    m12v[1] = (v2f){MSCALE * (v12b.x + v21b.x), MSCALE * (v12b.y + v21b.y)};
    m22v[0] = (v2f){MSCALE * v22a.x, MSCALE * v22a.y};
    m22v[1] = (v2f){MSCALE * v22b.x, MSCALE * v22b.y};

    const bool bL = (x0 > 0);
    const bool bR = (x0 < W - 1);
    const int  xL = bL ? x0 - 1 : 0;
    const int  xR = bR ? x0 + 1 : W - 1;
    const float f2xL = (float)(2 * xL);
    const float f2xC = (float)(2 * x0);
    const float f2xR = (float)(2 * xR);
    const float xf0  = f2xC;
    const float yf0  = (float)(2 * y0);
    const float INF  = __builtin_inff();

    v2f sumwv[2] = {(v2f){0.f,0.f}, (v2f){0.f,0.f}};
    v2f acc0v[2] = {(v2f){0.f,0.f}, (v2f){0.f,0.f}};
    v2f acc1v[2] = {(v2f){0.f,0.f}, (v2f){0.f,0.f}};
    v2f acc2v[2] = {(v2f){0.f,0.f}, (v2f){0.f,0.f}};

    __syncthreads();    // staging complete

#define COLK(or_, oc_, q_, a0_, a1_, a2_, f2x_, COLB, IS_L, NEED_VY)          \
    {                                                                         \
        const float posr = fmaf(or_, 2.0f, rowf);                             \
        const float dy0v = posr - yf0;                                        \
        const float dy1v = dy0v - 1.0f;                                       \
        const float posc = fmaf(oc_, 2.0f, f2x_);                             \
        const float dx0v = posc - xf0;                                        \
        const float dx1v = dx0v - 1.0f;                                       \
        const v2f dxv = (v2f){dx0v, dx1v};                                    \
        const bool vx1 = IS_L ? (dx1v >= -RADIUS) : true;                     \
        _Pragma("unroll")                                                     \
        for (int sy = 0; sy < 2; ++sy) {                                      \
            const float dyv = sy ? dy1v : dy0v;                               \
            const bool okb = (COLB) && (NEED_VY && sy ? (dy1v >= -RADIUS)     \
                                                      : true);                \
            const v2f u = dxv * m11v[sy] + dyv * m12v[sy];                    \
            v2f dv = dxv * u + (dyv * dyv) * m22v[sy];                        \
            dv = __builtin_elementwise_min(dv, (v2f){CLHI, CLHI});            \
            const float f0 = okb ? dv.x : INF;                                \
            const float f1 = (okb && vx1) ? dv.y : INF;                       \
            const v2f ev  = (v2f){exp2f(-f0), exp2f(-f1)};                    \
            const v2f wv2 = ev * (q_);                                        \
            sumwv[sy] += wv2;                                                 \
            acc0v[sy] += wv2 * (a0_);                                         \
            acc1v[sy] += wv2 * (a1_);                                         \
            acc2v[sy] += wv2 * (a2_);                                         \
        }                                                                     \
    }

    #pragma unroll
    for (int ai = 0; ai < 2; ++ai) {
        const int a    = af0 + ai;          // wave-uniform
        const int segA = a * 18;
        #pragma unroll
        for (int dr = 0; dr < 3; ++dr) {    // dr = di + 1
            if (dr == 0 && y0 == 0) continue;       // scalar uniform skip
            if (dr == 2 && y0 == H - 1) continue;
            const float rowf = (float)(2 * (y0 + dr - 1));
            const int b0 = (segA + dr) * SEGW + 3 + pix;    // p=0
            const int b1 = b0 + 3 * SEGW;
            const int b2 = b0 + 6 * SEGW;
            const int b3 = b0 + 9 * SEGW;
            const int b4 = b0 + 12 * SEGW;
            const int b5 = b0 + 15 * SEGW;
            const float orL = lds[b0],     orC = lds[b0 + 1], orR = lds[b0 + 2];
            const float ocL = lds[b1],     ocC = lds[b1 + 1], ocR = lds[b1 + 2];
            const float qL  = lds[b2],     qC  = lds[b2 + 1], qR  = lds[b2 + 2];
            const float aL0 = lds[b3],     aC0 = lds[b3 + 1], aR0 = lds[b3 + 2];
            const float aL1 = lds[b4],     aC1 = lds[b4 + 1], aR1 = lds[b4 + 2];
            const float aL2 = lds[b5],     aC2 = lds[b5 + 1], aR2 = lds[b5 + 2];

            const bool needvy = (dr == 0);
            COLK(orL, ocL, qL, aL0, aL1, aL2, f2xL, bL,   true,  needvy)
            COLK(orC, ocC, qC, aC0, aC1, aC2, f2xC, true, false, needvy)
            COLK(orR, ocR, qR, aR0, aR1, aR2, f2xR, bR,   false, needvy)
        }
    }
#undef COLK

    // ---- cross-fpair reduction (aliases staging LDS) ----
    __syncthreads();    // all compute reads of staging done
    if (fpair == 1) {
        float* r = &lds[pix * 17];
        #pragma unroll
        for (int sy = 0; sy < 2; ++sy) {
            r[sy*8+0] = sumwv[sy].x; r[sy*8+1] = sumwv[sy].y;
            r[sy*8+2] = acc0v[sy].x; r[sy*8+3] = acc0v[sy].y;
            r[sy*8+4] = acc1v[sy].x; r[sy*8+5] = acc1v[sy].y;
            r[sy*8+6] = acc2v[sy].x; r[sy*8+7] = acc2v[sy].y;
        }
    }
    __syncthreads();
    if (fpair == 0) {
        const float* r = &lds[pix * 17];
        #pragma unroll
        for (int sy = 0; sy < 2; ++sy) {
            sumwv[sy].x += r[sy*8+0]; sumwv[sy].y += r[sy*8+1];
            acc0v[sy].x += r[sy*8+2]; acc0v[sy].y += r[sy*8+3];
            acc1v[sy].x += r[sy*8+4]; acc1v[sy].y += r[sy*8+5];
            acc2v[sy].x += r[sy*8+6]; acc2v[sy].y += r[sy*8+7];
        }
        const size_t ob = (size_t)(nn * CH) * SHW + (size_t)(2 * y0) * SW + 2 * x0;
        #pragma unroll
        for (int sy = 0; sy < 2; ++sy) {
            const v2f inv = (v2f){1.0f / sumwv[sy].x, 1.0f / sumwv[sy].y};
            const v2f r0 = acc0v[sy] * inv;
            const v2f r1 = acc1v[sy] * inv;
            const v2f r2 = acc2v[sy] * inv;
            *(float2*)(out + ob + (size_t)sy * SW)         = make_float2(r0.x, r0.y);
            *(float2*)(out + ob + (size_t)sy * SW + SHW)   = make_float2(r1.x, r1.y);
            *(float2*)(out + ob + (size_t)sy * SW + 2*SHW) = make_float2(r2.x, r2.y);
        }
    }
}

extern "C" void kernel_launch(void* const* d_in, const int* in_sizes, int n_in,
                              void* d_out, int out_size, void* d_ws, size_t ws_size,
                              hipStream_t stream) {
    const float* alts    = (const float*)d_in[0];
    const float* offsets = (const float*)d_in[1];
    const float* qs      = (const float*)d_in[2];
    const float* o11     = (const float*)d_in[3];
    const float* o12     = (const float*)d_in[4];
    const float* o21     = (const float*)d_in[5];
    const float* o22     = (const float*)d_in[6];
    float* out = (float*)d_out;

    const int total_threads = NB * H * W * 2;   // 524,288
    const int block = 256;
    const int grid  = total_threads / block;    // 2048
    superresolve_kernel<<<grid, block, 0, stream>>>(alts, offsets, qs,
                                                    o11, o12, o21, o22, out);
}

// Round 8
// 23.625 us; speedup vs baseline: 1.3164x; 1.3164x over previous
//
#include <hip/hip_runtime.h>

// SuperResolve: A=4 frames, n=4, c=3, h=w=256, S=2 -> out (4,3,512,512) fp32
// R8 = R6 structure (best: 26us) + VALU de-fat. R6 was VALU-issue bound
// (derived from R4 counters: ~5K emitted instrs/thread vs ~1.2K source).
// Changes: raw v_exp_f32 via __builtin_amdgcn_exp2f (kills OCML guard code;
// arg in [-14.4,0] is guard-free); scalar math (no v2f scalarization churn);
// bL/bR masks premultiplied into q once per (a,row) instead of per-subpixel
// select chains; dy/dx via folded per-lane constants (1 fma each).
// R3: no waves/EU cap (spills). R4: >=2048 blocks. R6: SGPR plane bases.
// R7: LDS staging regressed (occupancy halved, added LDS ops while VALU-bound).

#define AF      4
#define NB      4
#define CH      3
#define H       256
#define W       256
#define SH      512
#define SW      512
#define HW      (H*W)
#define SHW     (SH*SW)
#define RADIUS  4.0f
// 0.25 (LR displacement scaling) * 0.5*log2(e): weight = exp2(-dist')
#define MSCALE  0.18033688011112042f
// clamp-hi: 20 * 0.5*log2(e)
#define CLHI    14.426950408889634f

__global__ __launch_bounds__(256) void superresolve_kernel(
    const float* __restrict__ alts,     // [AF][NB][CH][H][W]
    const float* __restrict__ offsets,  // [AF][NB][2][H][W]
    const float* __restrict__ qs,       // [AF][NB][H][W]
    const float* __restrict__ o11,      // [NB][SH][SW]
    const float* __restrict__ o12,
    const float* __restrict__ o21,
    const float* __restrict__ o22,
    float* __restrict__ out)            // [NB][CH][SH][SW]
{
    __shared__ float red[128 * 17];     // stride 17 words: conflict-free

    const int tid   = threadIdx.x;
    const int wv    = tid >> 6;
    const int lane  = tid & 63;
    const int fpair = wv >> 1;                  // 0: frames {0,1}; 1: {2,3}
    const int pix   = ((wv & 1) << 6) + lane;   // 0..127

    // bijective XCD swizzle over 2048 blocks
    const int bid = blockIdx.x;
    const int swz = (bid & 7) * 256 + (bid >> 3);
    const int P   = swz * 128 + pix;            // linear LR pixel id

    const int x0 = P & (W - 1);
    // wave-uniform -> SGPRs
    const int y0  = __builtin_amdgcn_readfirstlane((P >> 8) & (H - 1));
    const int nn  = __builtin_amdgcn_readfirstlane(P >> 16);
    const int af0 = __builtin_amdgcn_readfirstlane(fpair << 1);

    const bool bL = (x0 > 0);
    const bool bR = (x0 < W - 1);
    const int  xL = bL ? x0 - 1 : 0;
    const int  xR = bR ? x0 + 1 : W - 1;
    const int  iL = y0 * W + xL;
    const int  iC = y0 * W + x0;
    const int  iR = y0 * W + xR;
    // folded dx base constants: 2*(xcol - x0)
    const float cxL = (float)(2 * (xL - x0));   // -2 (or 0 at left edge)
    const float cxC = 0.0f;
    const float cxR = (float)(2 * (xR - x0));   // +2 (or 0 at right edge)

    // per-subpixel o-matrices (float2 loads, coalesced)
    const int obase = (nn * SH + 2 * y0) * SW + 2 * x0;
    const float2 v11a = *(const float2*)(o11 + obase);
    const float2 v11b = *(const float2*)(o11 + obase + SW);
    const float2 v12a = *(const float2*)(o12 + obase);
    const float2 v12b = *(const float2*)(o12 + obase + SW);
    const float2 v21a = *(const float2*)(o21 + obase);
    const float2 v21b = *(const float2*)(o21 + obase + SW);
    const float2 v22a = *(const float2*)(o22 + obase);
    const float2 v22b = *(const float2*)(o22 + obase + SW);

    float m11s[2][2], m12s[2][2], m22s[2][2];
    m11s[0][0] = MSCALE * v11a.x;  m11s[0][1] = MSCALE * v11a.y;
    m11s[1][0] = MSCALE * v11b.x;  m11s[1][1] = MSCALE * v11b.y;
    m12s[0][0] = MSCALE * (v12a.x + v21a.x);  m12s[0][1] = MSCALE * (v12a.y + v21a.y);
    m12s[1][0] = MSCALE * (v12b.x + v21b.x);  m12s[1][1] = MSCALE * (v12b.y + v21b.y);
    m22s[0][0] = MSCALE * v22a.x;  m22s[0][1] = MSCALE * v22a.y;
    m22s[1][0] = MSCALE * v22b.x;  m22s[1][1] = MSCALE * v22b.y;

    float sumw[2][2] = {{0.f,0.f},{0.f,0.f}};
    float acc0[2][2] = {{0.f,0.f},{0.f,0.f}};
    float acc1[2][2] = {{0.f,0.f},{0.f,0.f}};
    float acc2[2][2] = {{0.f,0.f},{0.f,0.f}};

    // COLK: one (a,row,column) contribution to all 4 subpixels.
    // IS_L / NEED_VY are compile-time; q_ is pre-masked for column bounds.
#define COLK(or_, oc_, q_, a0_, a1_, a2_, cx_, IS_L, NEED_VY)                 \
    {                                                                         \
        const float dy0v = fmaf(or_, 2.0f, dyc);                              \
        const float dy1v = dy0v - 1.0f;                                       \
        const float dx0v = fmaf(oc_, 2.0f, cx_);                              \
        const float dx1v = dx0v - 1.0f;                                       \
        const bool vx1 = !(IS_L) || (dx1v >= -RADIUS);                        \
        const bool vyb = !(NEED_VY) || (dy1v >= -RADIUS);                     \
        _Pragma("unroll")                                                     \
        for (int sy = 0; sy < 2; ++sy) {                                      \
            const float dyv = sy ? dy1v : dy0v;                               \
            const float dy2 = dyv * dyv;                                      \
            _Pragma("unroll")                                                 \
            for (int sx = 0; sx < 2; ++sx) {                                  \
                const float dxv = sx ? dx1v : dx0v;                           \
                const float u = fmaf(dyv, m12s[sy][sx], dxv * m11s[sy][sx]);  \
                float d = fmaf(dxv, u, dy2 * m22s[sy][sx]);                   \
                d = fminf(d, CLHI);                                           \
                float w = __builtin_amdgcn_exp2f(-d) * (q_);                  \
                if (IS_L && sx == 1)    w = vx1 ? w : 0.0f;                   \
                if (NEED_VY && sy == 1) w = vyb ? w : 0.0f;                   \
                sumw[sy][sx] += w;                                            \
                acc0[sy][sx] = fmaf(w, a0_, acc0[sy][sx]);                    \
                acc1[sy][sx] = fmaf(w, a1_, acc1[sy][sx]);                    \
                acc2[sy][sx] = fmaf(w, a2_, acc2[sy][sx]);                    \
            }                                                                 \
        }                                                                     \
    }

    #pragma unroll
    for (int ai = 0; ai < 2; ++ai) {
        const int a = af0 + ai;   // wave-uniform scalar
        const float* offbR = offsets + (size_t)(a * NB + nn) * 2 * HW;
        const float* offbC = offbR + HW;
        const float* qb    = qs   + (size_t)(a * NB + nn) * HW;
        const float* ab0   = alts + (size_t)(a * NB + nn) * CH * HW;
        const float* ab1   = ab0 + HW;
        const float* ab2   = ab0 + 2 * HW;

        #pragma unroll
        for (int dr = 0; dr < 3; ++dr) {        // dr = di + 1
            if (dr == 0 && y0 == 0) continue;   // scalar uniform skip
            if (dr == 2 && y0 == H - 1) continue;
            const int ro = (dr - 1) * W;        // scalar row offset
            const float* pR = offbR + ro;
            const float* pC = offbC + ro;
            const float* pQ = qb + ro;
            const float* p0 = ab0 + ro;
            const float* p1 = ab1 + ro;
            const float* p2 = ab2 + ro;
            const float dyc = (float)(2 * (dr - 1));   // 2*di

            // 18 batched gathers (saddr + {iL,iC,iR})
            const float orL = pR[iL], orC = pR[iC], orR = pR[iR];
            const float ocL = pC[iL], ocC = pC[iC], ocR = pC[iR];
            const float qL  = pQ[iL], qC  = pQ[iC], qR  = pQ[iR];
            const float aL0 = p0[iL], aC0 = p0[iC], aR0 = p0[iR];
            const float aL1 = p1[iL], aC1 = p1[iC], aR1 = p1[iR];
            const float aL2 = p2[iL], aC2 = p2[iC], aR2 = p2[iR];

            // column-bounds masks folded into q (once, not per subpixel)
            const float qLm = bL ? qL : 0.0f;
            const float qRm = bR ? qR : 0.0f;

            const bool needvy = (dr == 0);
            COLK(orL, ocL, qLm, aL0, aL1, aL2, cxL, true,  needvy)
            COLK(orC, ocC, qC,  aC0, aC1, aC2, cxC, false, needvy)
            COLK(orR, ocR, qRm, aR0, aR1, aR2, cxR, false, needvy)
        }
    }
#undef COLK

    // cross-fpair reduction: fpair 1 writes 16 floats/pixel, fpair 0 sums+stores
    if (fpair == 1) {
        float* r = &red[pix * 17];
        #pragma unroll
        for (int sy = 0; sy < 2; ++sy)
            #pragma unroll
            for (int sx = 0; sx < 2; ++sx) {
                const int s = sy * 2 + sx;
                r[s]      = sumw[sy][sx];
                r[4 + s]  = acc0[sy][sx];
                r[8 + s]  = acc1[sy][sx];
                r[12 + s] = acc2[sy][sx];
            }
    }
    __syncthreads();
    if (fpair == 0) {
        const float* r = &red[pix * 17];
        #pragma unroll
        for (int sy = 0; sy < 2; ++sy)
            #pragma unroll
            for (int sx = 0; sx < 2; ++sx) {
                const int s = sy * 2 + sx;
                sumw[sy][sx] += r[s];
                acc0[sy][sx] += r[4 + s];
                acc1[sy][sx] += r[8 + s];
                acc2[sy][sx] += r[12 + s];
            }
        const size_t ob = (size_t)(nn * CH) * SHW + (size_t)(2 * y0) * SW + 2 * x0;
        #pragma unroll
        for (int sy = 0; sy < 2; ++sy) {
            const float i0 = 1.0f / sumw[sy][0];
            const float i1 = 1.0f / sumw[sy][1];
            *(float2*)(out + ob + (size_t)sy * SW) =
                make_float2(acc0[sy][0] * i0, acc0[sy][1] * i1);
            *(float2*)(out + ob + (size_t)sy * SW + SHW) =
                make_float2(acc1[sy][0] * i0, acc1[sy][1] * i1);
            *(float2*)(out + ob + (size_t)sy * SW + 2 * SHW) =
                make_float2(acc2[sy][0] * i0, acc2[sy][1] * i1);
        }
    }
}

extern "C" void kernel_launch(void* const* d_in, const int* in_sizes, int n_in,
                              void* d_out, int out_size, void* d_ws, size_t ws_size,
                              hipStream_t stream) {
    const float* alts    = (const float*)d_in[0];
    const float* offsets = (const float*)d_in[1];
    const float* qs      = (const float*)d_in[2];
    const float* o11     = (const float*)d_in[3];
    const float* o12     = (const float*)d_in[4];
    const float* o21     = (const float*)d_in[5];
    const float* o22     = (const float*)d_in[6];
    float* out = (float*)d_out;

    const int total_threads = NB * H * W * 2;   // 524,288
    const int block = 256;
    const int grid  = total_threads / block;    // 2048
    superresolve_kernel<<<grid, block, 0, stream>>>(alts, offsets, qs,
                                                    o11, o12, o21, o22, out);
}